// Round 4
// baseline (186.380 us; speedup 1.0000x reference)
//
#include <hip/hip_runtime.h>
#include <hip/hip_fp16.h>

#define N_NODES 50000
#define N_EDGES 800000
#define D 64
#define DHID 100
#define NTILES (N_NODES / 16)                   // 3125
#define NCT 7                                   // head col-tiles (112 cols padded)
#define CAP 64                                  // fixed slots per node (32 per parity)
#define NGROUPS 4                               // dst-range groups
#define NSLICES 780                             // fill blocks per group
#define FILL_BLOCKS (NGROUPS * NSLICES)         // 3120
#define MM_BLOCKS ((NTILES + 3) / 4)            // 782
#define DST_PER_GROUP (N_NODES / NGROUPS)       // 12500
#define FSTRIDE (NSLICES * 256)                 // 199680
#define KMAX 5                                  // scan iterations per thread (4 full + ragged)

typedef unsigned short ushort;
typedef unsigned int uint;
typedef __attribute__((ext_vector_type(8))) short s16x8;
typedef __attribute__((ext_vector_type(4))) float f32x4;

#define MFMA16(A, B, C) __builtin_amdgcn_mfma_f32_16x16x32_bf16((A), (B), (C), 0, 0, 0)

__device__ __forceinline__ float swishf(float x) { return x / (1.0f + __expf(-x)); }

__device__ __forceinline__ ushort f2bf(float f) {   // RTNE fp32 -> bf16
    uint u = __float_as_uint(f);
    uint r = (u + 0x7fffu + ((u >> 16) & 1u)) >> 16;
    return (ushort)r;
}
__device__ __forceinline__ float bf2f(ushort h) { return __uint_as_float((uint)h << 16); }
__device__ __forceinline__ float bf_lo(uint d) { return __uint_as_float(d << 16); }
__device__ __forceinline__ float bf_hi(uint d) { return __uint_as_float(d & 0xffff0000u); }

__device__ __forceinline__ float hwf(uint e) {
    return __half2float(__ushort_as_half((ushort)(e >> 16)));
}

__device__ __forceinline__ void accum8(float* acc, uint4 v, float w) {
    acc[0] = fmaf(w, bf_lo(v.x), acc[0]);
    acc[1] = fmaf(w, bf_hi(v.x), acc[1]);
    acc[2] = fmaf(w, bf_lo(v.y), acc[2]);
    acc[3] = fmaf(w, bf_hi(v.y), acc[3]);
    acc[4] = fmaf(w, bf_lo(v.z), acc[4]);
    acc[5] = fmaf(w, bf_hi(v.z), acc[5]);
    acc[6] = fmaf(w, bf_lo(v.w), acc[6]);
    acc[7] = fmaf(w, bf_hi(v.w), acc[7]);
}

// 2-nodes-per-wave gather over PARITY-SPLIT buckets:
//   parity 0 edges in slots [0,32) counted by deg2[2n], parity 1 in [32,64)
//   counted by deg2[2n+1] (each ~Poisson(8)).
// Grain A = parity-0 slots j*4.., grain B = parity-1 slots j*4.. ;
// chain = [2 bucket lines || deg2 pair] -> [up to 8 row loads, one window].
// P(parity deg > 16) ~ 0.3% -> tail loops are rare.
__device__ __forceinline__ void gather_node2(const ushort* __restrict__ H,
                                             const uint* __restrict__ bucket,
                                             const int* __restrict__ degp,   // &deg2[2*node]
                                             int j, int fg, float* acc) {
#pragma unroll
    for (int t = 0; t < 8; ++t) acc[t] = 0.f;
    const int sj = j * 4;
    uint4 eA = *((const uint4*)(bucket + sj));        // parity-0 grain
    uint4 eB = *((const uint4*)(bucket + 32 + sj));   // parity-1 grain
    int2 dd = *((const int2*)degp);                   // concurrent with buckets
    int dA = min(dd.x, 32), dB = min(dd.y, 32);

    bool pA = sj < dA, pB = sj < dB;
    uint4 vA0, vA1, vA2, vA3, vB0, vB1, vB2, vB3;
    float wA0 = 0, wA1 = 0, wA2 = 0, wA3 = 0;
    float wB0 = 0, wB1 = 0, wB2 = 0, wB3 = 0;
    if (pA) {                                        // issue A row loads
        wA0 = hwf(eA.x);
        wA1 = (sj + 1 < dA) ? hwf(eA.y) : 0.f;
        wA2 = (sj + 2 < dA) ? hwf(eA.z) : 0.f;
        wA3 = (sj + 3 < dA) ? hwf(eA.w) : 0.f;
        uint i0 = min(eA.x & 0xffffu, (uint)(N_NODES - 1));
        uint i1 = min(eA.y & 0xffffu, (uint)(N_NODES - 1));
        uint i2 = min(eA.z & 0xffffu, (uint)(N_NODES - 1));
        uint i3 = min(eA.w & 0xffffu, (uint)(N_NODES - 1));
        vA0 = *((const uint4*)(H + ((size_t)i0 << 6) + (fg << 3)));
        vA1 = *((const uint4*)(H + ((size_t)i1 << 6) + (fg << 3)));
        vA2 = *((const uint4*)(H + ((size_t)i2 << 6) + (fg << 3)));
        vA3 = *((const uint4*)(H + ((size_t)i3 << 6) + (fg << 3)));
    }
    if (pB) {                                        // issue B row loads before A's FMAs
        wB0 = hwf(eB.x);
        wB1 = (sj + 1 < dB) ? hwf(eB.y) : 0.f;
        wB2 = (sj + 2 < dB) ? hwf(eB.z) : 0.f;
        wB3 = (sj + 3 < dB) ? hwf(eB.w) : 0.f;
        uint i0 = min(eB.x & 0xffffu, (uint)(N_NODES - 1));
        uint i1 = min(eB.y & 0xffffu, (uint)(N_NODES - 1));
        uint i2 = min(eB.z & 0xffffu, (uint)(N_NODES - 1));
        uint i3 = min(eB.w & 0xffffu, (uint)(N_NODES - 1));
        vB0 = *((const uint4*)(H + ((size_t)i0 << 6) + (fg << 3)));
        vB1 = *((const uint4*)(H + ((size_t)i1 << 6) + (fg << 3)));
        vB2 = *((const uint4*)(H + ((size_t)i2 << 6) + (fg << 3)));
        vB3 = *((const uint4*)(H + ((size_t)i3 << 6) + (fg << 3)));
    }
    if (pA) {
        accum8(acc, vA0, wA0);
        accum8(acc, vA1, wA1);
        accum8(acc, vA2, wA2);
        accum8(acc, vA3, wA3);
    }
    if (pB) {
        accum8(acc, vB0, wB0);
        accum8(acc, vB1, wB1);
        accum8(acc, vB2, wB2);
        accum8(acc, vB3, wB3);
    }
    // rare tails: parity deg in (16,32]
    if (dA > 16) {
        int s0 = 16 + sj;
        if (s0 < dA) {
            uint4 e = *((const uint4*)(bucket + s0));
            float w0 = hwf(e.x);
            float w1 = (s0 + 1 < dA) ? hwf(e.y) : 0.f;
            float w2 = (s0 + 2 < dA) ? hwf(e.z) : 0.f;
            float w3 = (s0 + 3 < dA) ? hwf(e.w) : 0.f;
            uint i0 = min(e.x & 0xffffu, (uint)(N_NODES - 1));
            uint i1 = min(e.y & 0xffffu, (uint)(N_NODES - 1));
            uint i2 = min(e.z & 0xffffu, (uint)(N_NODES - 1));
            uint i3 = min(e.w & 0xffffu, (uint)(N_NODES - 1));
            uint4 v0 = *((const uint4*)(H + ((size_t)i0 << 6) + (fg << 3)));
            uint4 v1 = *((const uint4*)(H + ((size_t)i1 << 6) + (fg << 3)));
            uint4 v2 = *((const uint4*)(H + ((size_t)i2 << 6) + (fg << 3)));
            uint4 v3 = *((const uint4*)(H + ((size_t)i3 << 6) + (fg << 3)));
            accum8(acc, v0, w0);
            accum8(acc, v1, w1);
            accum8(acc, v2, w2);
            accum8(acc, v3, w3);
        }
    }
    if (dB > 16) {
        int s0 = 16 + sj;
        if (s0 < dB) {
            uint4 e = *((const uint4*)(bucket + 32 + s0));
            float w0 = hwf(e.x);
            float w1 = (s0 + 1 < dB) ? hwf(e.y) : 0.f;
            float w2 = (s0 + 2 < dB) ? hwf(e.z) : 0.f;
            float w3 = (s0 + 3 < dB) ? hwf(e.w) : 0.f;
            uint i0 = min(e.x & 0xffffu, (uint)(N_NODES - 1));
            uint i1 = min(e.y & 0xffffu, (uint)(N_NODES - 1));
            uint i2 = min(e.z & 0xffffu, (uint)(N_NODES - 1));
            uint i3 = min(e.w & 0xffffu, (uint)(N_NODES - 1));
            uint4 v0 = *((const uint4*)(H + ((size_t)i0 << 6) + (fg << 3)));
            uint4 v1 = *((const uint4*)(H + ((size_t)i1 << 6) + (fg << 3)));
            uint4 v2 = *((const uint4*)(H + ((size_t)i2 << 6) + (fg << 3)));
            uint4 v3 = *((const uint4*)(H + ((size_t)i3 << 6) + (fg << 3)));
            accum8(acc, v0, w0);
            accum8(acc, v1, w1);
            accum8(acc, v2, w2);
            accum8(acc, v3, w3);
        }
    }
    // reduce over the 4 quads of each 32-lane half (xor 8,16 stay in-half)
#pragma unroll
    for (int t = 0; t < 8; ++t) {
        acc[t] += __shfl_xor(acc[t], 8, 64);
        acc[t] += __shfl_xor(acc[t], 16, 64);
    }
}

// ---- fused: XCD-partitioned fill + H1 = X@W1 + weight-split prep (2 blocks) ----
__global__ __launch_bounds__(256) void fill_and_l1(const int* __restrict__ src,
                                                   const int* __restrict__ dst,
                                                   const float* __restrict__ w,
                                                   int* __restrict__ deg2,
                                                   uint* __restrict__ csr,
                                                   const float* __restrict__ X,
                                                   const float* __restrict__ W,
                                                   const float* __restrict__ W2,
                                                   const float* __restrict__ Wd,
                                                   short* __restrict__ W2T2,
                                                   short* __restrict__ WdT2,
                                                   ushort* __restrict__ H) {
    __shared__ __align__(16) short sBT[2][D][72];    // 18.4 KB (aliased as rep later)
    int tid = threadIdx.x;

    if (blockIdx.x < FILL_BLOCKS) {
        // PARITY-SPLIT single-XCD csr line ownership:
        //   bid mod 8 = p*4 + g  ->  one XCD per (group, parity) under
        //   round-robin dispatch. Parity-p blocks write ONLY slots
        //   [p*32, p*32+32) of each bucket = exactly one 128B line, with its
        //   own counter deg2[2d+p]. No csr line is dirtied by two XCDs.
        // dst stays CACHED (re-scanned 4x, must be L2/L3 resident);
        // src/w are NT (read exactly once -> keep them out of L2 so they
        // don't evict partially-written csr lines).
        const int g = blockIdx.x & (NGROUPS - 1);
        const int s = blockIdx.x >> 2;               // slice 0..NSLICES-1
        const int p = s & 1;                         // parity -> unique XCD
        const int lo = g * DST_PER_GROUP;
        const int e0 = s * 256 + tid;
        int d[KMAX];
        bool mk[KMAX];
#pragma unroll
        for (int k = 0; k < KMAX; ++k) {
            int e = e0 + k * FSTRIDE;
            int dv = (e < N_EDGES) ? dst[e] : -1;
            d[k] = dv;
            mk[k] = ((uint)(dv - lo) < (uint)DST_PER_GROUP);
        }
        float wv5[KMAX];
        int sv5[KMAX];
#pragma unroll
        for (int k = 0; k < KMAX; ++k)
            if (mk[k]) {
                int e = e0 + k * FSTRIDE;
                wv5[k] = __builtin_nontemporal_load(w + e);
                sv5[k] = __builtin_nontemporal_load(src + e);
            }
        int r5[KMAX];
#pragma unroll
        for (int k = 0; k < KMAX; ++k)
            if (mk[k]) r5[k] = atomicAdd(&deg2[(d[k] << 1) + p], 1);
#pragma unroll
        for (int k = 0; k < KMAX; ++k)
            if (mk[k]) {
                uint hw = (uint)__half_as_ushort(__float2half_rn(wv5[k]));
                uint payload = (uint)sv5[k] | (hw << 16);
                int r = min(r5[k], 31);              // per-parity cap 32 (safety clamp)
                csr[(d[k] << 6) + (p << 5) + r] = payload;
            }
        return;
    }

    if (blockIdx.x >= FILL_BLOCKS + MM_BLOCKS) {
        // ---------- weight-split prep ----------
        if (blockIdx.x == FILL_BLOCKS + MM_BLOCKS) {
            for (int idx = tid; idx < D * D; idx += 256) {
                int k = idx >> 6, c = idx & 63;
                float wv = W2[idx];
                ushort hi = f2bf(wv);
                W2T2[(size_t)c * D + k] = (short)hi;
                W2T2[(size_t)(D + c) * D + k] = (short)f2bf(wv - bf2f(hi));
            }
        } else {
            for (int idx = tid; idx < NCT * 16 * D; idx += 256) {
                int jj = idx >> 6, k = idx & 63;
                float wv = (jj < DHID) ? Wd[k * DHID + jj] : 0.f;
                ushort hi = f2bf(wv);
                WdT2[(size_t)jj * D + k] = (short)hi;
                WdT2[(size_t)(NCT * 16 + jj) * D + k] = (short)f2bf(wv - bf2f(hi));
            }
        }
        return;
    }

    // ---------- mfma_l1 path ----------
    for (int idx = tid; idx < D * D; idx += 256) {
        int k = idx >> 6, c = idx & 63;
        float wv = W[idx];
        ushort hi = f2bf(wv);
        sBT[0][c][k] = (short)hi;
        sBT[1][c][k] = (short)f2bf(wv - bf2f(hi));
    }
    __syncthreads();
    int wv_ = tid >> 6, lane = tid & 63, quad = lane >> 4, m = lane & 15;
    int tile = min((blockIdx.x - FILL_BLOCKS) * 4 + wv_, NTILES - 1);  // clamp (dup stores ok)
    int node0 = tile * 16;

    f32x4 acc[4] = {{0,0,0,0},{0,0,0,0},{0,0,0,0},{0,0,0,0}};
#pragma unroll
    for (int kt = 0; kt < 2; ++kt) {
        int k0 = kt * 32 + quad * 8;
        const float* xp = X + ((size_t)(node0 + m) << 6) + k0;
        f32x4 xa = __builtin_nontemporal_load((const f32x4*)xp);   // NT: X read-once
        f32x4 xb = __builtin_nontemporal_load((const f32x4*)(xp + 4));
        float xv[8] = {xa[0], xa[1], xa[2], xa[3], xb[0], xb[1], xb[2], xb[3]};
        s16x8 ahi, alo;
#pragma unroll
        for (int jj = 0; jj < 8; ++jj) {
            ushort hi = f2bf(xv[jj]);
            ahi[jj] = (short)hi;
            alo[jj] = (short)f2bf(xv[jj] - bf2f(hi));
        }
#pragma unroll
        for (int ct = 0; ct < 4; ++ct) {
            int n = ct * 16 + m;
            s16x8 bhi = *((const s16x8*)&sBT[0][n][k0]);
            s16x8 blo = *((const s16x8*)&sBT[1][n][k0]);
            acc[ct] = MFMA16(ahi, bhi, acc[ct]);
            acc[ct] = MFMA16(ahi, blo, acc[ct]);
            acc[ct] = MFMA16(alo, bhi, acc[ct]);
        }
    }
    __syncthreads();   // safe to alias rep over sBT
    short (*rep)[16][72] = (short(*)[16][72])&sBT[0][0][0];
#pragma unroll
    for (int ct = 0; ct < 4; ++ct)
#pragma unroll
        for (int r = 0; r < 4; ++r)
            rep[wv_][quad * 4 + r][ct * 16 + m] = (short)f2bf(acc[ct][r]);
#pragma unroll
    for (int half = 0; half < 2; ++half) {
        int r = (lane >> 3) + half * 8;
        int c0 = (lane & 7) * 8;
        s16x8 v = *((const s16x8*)&rep[wv_][r][c0]);
        *((s16x8*)(H + ((size_t)(node0 + r) << 6) + c0)) = v;
    }
}

// ---------------- gather + bias + swish -> bf16 activation (layer 1) ----------------
// 2 nodes per wave: 8 nodes per 256-thread block.
__global__ __launch_bounds__(256) void gather_act(const ushort* __restrict__ H,
                                                  const int* __restrict__ deg2,
                                                  const uint* __restrict__ csr,
                                                  const float* __restrict__ bias,
                                                  ushort* __restrict__ actOut) {
    int tid = threadIdx.x;
    int wave = tid >> 6, lane = tid & 63;
    int h = lane >> 5, j = (lane >> 3) & 3, fg = lane & 7;
    int node = blockIdx.x * 8 + wave * 2 + h;
    const uint* bucket = csr + ((size_t)node << 6);

    float acc[8];
    gather_node2(H, bucket, deg2 + (node << 1), j, fg, acc);
    if (j == 0) {
        float4 ba = ((const float4*)bias)[fg * 2];
        float4 bb = ((const float4*)bias)[fg * 2 + 1];
        float r0 = swishf(acc[0] + ba.x);
        float r1 = swishf(acc[1] + ba.y);
        float r2 = swishf(acc[2] + ba.z);
        float r3 = swishf(acc[3] + ba.w);
        float r4 = swishf(acc[4] + bb.x);
        float r5 = swishf(acc[5] + bb.y);
        float r6 = swishf(acc[6] + bb.z);
        float r7 = swishf(acc[7] + bb.w);
        uint4 u;
        u.x = (uint)f2bf(r0) | ((uint)f2bf(r1) << 16);
        u.y = (uint)f2bf(r2) | ((uint)f2bf(r3) << 16);
        u.z = (uint)f2bf(r4) | ((uint)f2bf(r5) << 16);
        u.w = (uint)f2bf(r6) | ((uint)f2bf(r7) << 16);
        *((uint4*)(actOut + ((size_t)node << 6) + (fg << 3))) = u;
    }
}

// ---- fused: layer-2 gather + W2 matmul + bias + swish + MLP head, one 16-node tile/block ----
__global__ __launch_bounds__(256) void gather_tail(const ushort* __restrict__ act1,
                                                   const int* __restrict__ deg2,
                                                   const uint* __restrict__ csr,
                                                   const short* __restrict__ W2T2,
                                                   const float* __restrict__ b2,
                                                   const short* __restrict__ WdT2,
                                                   const float* __restrict__ bd,
                                                   const float* __restrict__ Wo,
                                                   const float* __restrict__ bo,
                                                   float* __restrict__ out) {
    __shared__ __align__(16) float sAgg[16][72];    // 4.6 KB fp32 aggregates
    __shared__ __align__(16) short sAct2[16][72];   // 2.3 KB bf16 act2 tile
    __shared__ float sPart[4][16];                  // per-wave head partials
    int tid = threadIdx.x;
    int wv = tid >> 6, lane = tid & 63;
    int h = lane >> 5, j = (lane >> 3) & 3, fg = lane & 7;
    int quad = lane >> 4, m = lane & 15;
    int node0 = blockIdx.x * 16;

    // ---- phase 0: gather 4 nodes per wave (2 per pass) ----
    for (int t = 0; t < 2; ++t) {
        int nl = wv * 4 + t * 2 + h;
        int node = node0 + nl;
        const uint* bucket = csr + ((size_t)node << 6);
        float acc[8];
        gather_node2(act1, bucket, deg2 + (node << 1), j, fg, acc);
        if (j == 0) {
            float4 u0 = {acc[0], acc[1], acc[2], acc[3]};
            float4 u1 = {acc[4], acc[5], acc[6], acc[7]};
            *((float4*)&sAgg[nl][fg * 8]) = u0;
            *((float4*)&sAgg[nl][fg * 8 + 4]) = u1;
        }
    }
    __syncthreads();

    // ---- phase A: act2 = swish(agg @ W2 + b2), wave wv -> col-tile wv ----
    {
        f32x4 acc = {0, 0, 0, 0};
        int n = wv * 16 + m;
#pragma unroll
        for (int kt = 0; kt < 2; ++kt) {
            int k0 = kt * 32 + quad * 8;
            float4 xa = *((const float4*)&sAgg[m][k0]);
            float4 xb = *((const float4*)&sAgg[m][k0 + 4]);
            float xv[8] = {xa.x, xa.y, xa.z, xa.w, xb.x, xb.y, xb.z, xb.w};
            s16x8 ahi, alo;
#pragma unroll
            for (int jj = 0; jj < 8; ++jj) {
                ushort hi = f2bf(xv[jj]);
                ahi[jj] = (short)hi;
                alo[jj] = (short)f2bf(xv[jj] - bf2f(hi));
            }
            s16x8 bhi = *((const s16x8*)(W2T2 + (size_t)n * D + k0));
            s16x8 blo = *((const s16x8*)(W2T2 + (size_t)(D + n) * D + k0));
            acc = MFMA16(ahi, bhi, acc);
            acc = MFMA16(ahi, blo, acc);
            acc = MFMA16(alo, bhi, acc);
        }
        float bv = b2[n];
#pragma unroll
        for (int r = 0; r < 4; ++r)
            sAct2[quad * 4 + r][n] = (short)f2bf(swishf(acc[r] + bv));
    }
    __syncthreads();

    // ---- phase B: head over col-tiles {wv, wv+4} ----
    float part[4] = {0, 0, 0, 0};
#pragma unroll
    for (int cc = 0; cc < 2; ++cc) {
        int ct = wv + cc * 4;
        if (ct < NCT) {
            f32x4 acc = {0, 0, 0, 0};
            int n = ct * 16 + m;
#pragma unroll
            for (int kt = 0; kt < 2; ++kt) {
                int k0 = kt * 32 + quad * 8;
                s16x8 a = *((const s16x8*)&sAct2[m][k0]);
                s16x8 bhi = *((const s16x8*)(WdT2 + (size_t)n * D + k0));
                s16x8 blo = *((const s16x8*)(WdT2 + (size_t)(NCT * 16 + n) * D + k0));
                acc = MFMA16(a, bhi, acc);
                acc = MFMA16(a, blo, acc);
            }
            float bdv = (n < DHID) ? bd[n] : 0.f;
            float wov = (n < DHID) ? Wo[n] : 0.f;
#pragma unroll
            for (int r = 0; r < 4; ++r)
                part[r] = fmaf(swishf(acc[r] + bdv), wov, part[r]);
        }
    }
#pragma unroll
    for (int r = 0; r < 4; ++r) {
        part[r] += __shfl_xor(part[r], 1, 64);
        part[r] += __shfl_xor(part[r], 2, 64);
        part[r] += __shfl_xor(part[r], 4, 64);
        part[r] += __shfl_xor(part[r], 8, 64);
    }
    if (m == 0) {
#pragma unroll
        for (int r = 0; r < 4; ++r)
            sPart[wv][quad * 4 + r] = part[r];
    }
    __syncthreads();
    if (tid < 16) {
        float z = sPart[0][tid] + sPart[1][tid] + sPart[2][tid] + sPart[3][tid] + bo[0];
        out[node0 + tid] = 1.f / (1.f + __expf(-z));
    }
}

extern "C" void kernel_launch(void* const* d_in, const int* in_sizes, int n_in,
                              void* d_out, int out_size, void* d_ws, size_t ws_size,
                              hipStream_t stream) {
    const float* x   = (const float*)d_in[0];
    const int* esrc  = (const int*)d_in[1];
    const int* edst  = (const int*)d_in[2];
    const float* ew  = (const float*)d_in[3];
    const float* W1  = (const float*)d_in[4];
    const float* b1  = (const float*)d_in[5];
    const float* W2  = (const float*)d_in[6];
    const float* b2  = (const float*)d_in[7];
    const float* Wd  = (const float*)d_in[8];
    const float* bd  = (const float*)d_in[9];
    const float* Wo  = (const float*)d_in[10];
    const float* bo  = (const float*)d_in[11];
    float* out = (float*)d_out;

    char* ws = (char*)d_ws;
    ushort* H1   = (ushort*)ws;  ws += (size_t)N_NODES * D * sizeof(ushort);   // 6.4 MB
    ushort* act1 = (ushort*)ws;  ws += (size_t)N_NODES * D * sizeof(ushort);   // 6.4 MB
    uint* csr    = (uint*)ws;    ws += (size_t)N_NODES * CAP * sizeof(uint);   // 12.8 MB (not zeroed)
    int* deg2    = (int*)ws;     ws += (size_t)2 * N_NODES * sizeof(int);      // 400 KB
    short* W2T2  = (short*)ws;   ws += (size_t)2 * D * D * sizeof(short);      // 16 KB
    short* WdT2  = (short*)ws;   ws += (size_t)2 * NCT * 16 * D * sizeof(short); // 28.7 KB

    const int gBlocks = N_NODES / 8;   // 6250 (2 nodes per wave)

    // ---- only deg2 needs zeroing (400 KB) ----
    hipMemsetAsync(deg2, 0, (size_t)2 * N_NODES * sizeof(int), stream);

    // ---- fused: XCD/parity-partitioned fill + layer-1 matmul + weight prep ----
    fill_and_l1<<<FILL_BLOCKS + MM_BLOCKS + 2, 256, 0, stream>>>(
        esrc, edst, ew, deg2, csr, x, W1, W2, Wd, W2T2, WdT2, H1);

    // ---- layer 1 gather (+bias+swish) ----
    gather_act<<<gBlocks, 256, 0, stream>>>(H1, deg2, csr, b1, act1);

    // ---- fused: layer-2 gather + W2 matmul + swish + MLP head ----
    gather_tail<<<NTILES, 256, 0, stream>>>(act1, deg2, csr, W2T2, b2, WdT2, bd, Wo, bo, out);
}

// Round 5
// 185.464 us; speedup vs baseline: 1.0049x; 1.0049x over previous
//
#include <hip/hip_runtime.h>
#include <hip/hip_fp16.h>

#define N_NODES 50000
#define N_EDGES 800000
#define D 64
#define DHID 100
#define NTILES (N_NODES / 16)                   // 3125
#define NCT 7                                   // head col-tiles (112 cols padded)
#define CAP 64                                  // fixed slots per node
#define NGROUPS 4                               // dst-range groups
#define NSLICES 780                             // fill blocks per group
#define FILL_BLOCKS (NGROUPS * NSLICES)         // 3120
#define MM_BLOCKS ((NTILES + 3) / 4)            // 782
#define DST_PER_GROUP (N_NODES / NGROUPS)       // 12500
#define FSTRIDE (NSLICES * 256)                 // 199680
#define KMAX 5                                  // scan iterations per thread (4 full + ragged)
#define GA_BLOCKS 1024                          // gather_act grid (grid-stride, pipelined)

typedef unsigned short ushort;
typedef unsigned int uint;
typedef __attribute__((ext_vector_type(8))) short s16x8;
typedef __attribute__((ext_vector_type(4))) float f32x4;

#define MFMA16(A, B, C) __builtin_amdgcn_mfma_f32_16x16x32_bf16((A), (B), (C), 0, 0, 0)

__device__ __forceinline__ float swishf(float x) { return x / (1.0f + __expf(-x)); }

__device__ __forceinline__ ushort f2bf(float f) {   // RTNE fp32 -> bf16
    uint u = __float_as_uint(f);
    uint r = (u + 0x7fffu + ((u >> 16) & 1u)) >> 16;
    return (ushort)r;
}
__device__ __forceinline__ float bf2f(ushort h) { return __uint_as_float((uint)h << 16); }
__device__ __forceinline__ float bf_lo(uint d) { return __uint_as_float(d << 16); }
__device__ __forceinline__ float bf_hi(uint d) { return __uint_as_float(d & 0xffff0000u); }

__device__ __forceinline__ float hwf(uint e) {
    return __half2float(__ushort_as_half((ushort)(e >> 16)));
}

__device__ __forceinline__ void accum8(float* acc, uint4 v, float w) {
    acc[0] = fmaf(w, bf_lo(v.x), acc[0]);
    acc[1] = fmaf(w, bf_hi(v.x), acc[1]);
    acc[2] = fmaf(w, bf_lo(v.y), acc[2]);
    acc[3] = fmaf(w, bf_hi(v.y), acc[3]);
    acc[4] = fmaf(w, bf_lo(v.z), acc[4]);
    acc[5] = fmaf(w, bf_hi(v.z), acc[5]);
    acc[6] = fmaf(w, bf_lo(v.w), acc[6]);
    acc[7] = fmaf(w, bf_hi(v.w), acc[7]);
}

// Gather body for one node, with the bucket's two 16-slot grains ALREADY in
// registers (eA = slots j*4.., eB = slots 16+j*4..) and degv resolved.
// Callers prefetch eA/eB/degv so the bucket latency overlaps other work.
// chain here = [up to 8 row loads, one window] -> FMA -> half-wave reduce.
__device__ __forceinline__ void gather_body(const ushort* __restrict__ H,
                                            const uint* __restrict__ bucket,  // rare tail only
                                            uint4 eA, uint4 eB, int degv,
                                            int j, int fg, float* acc) {
#pragma unroll
    for (int t = 0; t < 8; ++t) acc[t] = 0.f;
    const int sA = j * 4, sB = 16 + j * 4;
    bool pA = sA < degv, pB = sB < degv;
    uint4 vA0, vA1, vA2, vA3, vB0, vB1, vB2, vB3;
    float wA0 = 0, wA1 = 0, wA2 = 0, wA3 = 0;
    float wB0 = 0, wB1 = 0, wB2 = 0, wB3 = 0;
    if (pA) {                                        // issue A row loads
        wA0 = hwf(eA.x);
        wA1 = (sA + 1 < degv) ? hwf(eA.y) : 0.f;
        wA2 = (sA + 2 < degv) ? hwf(eA.z) : 0.f;
        wA3 = (sA + 3 < degv) ? hwf(eA.w) : 0.f;
        uint i0 = min(eA.x & 0xffffu, (uint)(N_NODES - 1));
        uint i1 = min(eA.y & 0xffffu, (uint)(N_NODES - 1));
        uint i2 = min(eA.z & 0xffffu, (uint)(N_NODES - 1));
        uint i3 = min(eA.w & 0xffffu, (uint)(N_NODES - 1));
        vA0 = *((const uint4*)(H + ((size_t)i0 << 6) + (fg << 3)));
        vA1 = *((const uint4*)(H + ((size_t)i1 << 6) + (fg << 3)));
        vA2 = *((const uint4*)(H + ((size_t)i2 << 6) + (fg << 3)));
        vA3 = *((const uint4*)(H + ((size_t)i3 << 6) + (fg << 3)));
    }
    if (pB) {                                        // issue B row loads before A's FMAs
        wB0 = hwf(eB.x);
        wB1 = (sB + 1 < degv) ? hwf(eB.y) : 0.f;
        wB2 = (sB + 2 < degv) ? hwf(eB.z) : 0.f;
        wB3 = (sB + 3 < degv) ? hwf(eB.w) : 0.f;
        uint i0 = min(eB.x & 0xffffu, (uint)(N_NODES - 1));
        uint i1 = min(eB.y & 0xffffu, (uint)(N_NODES - 1));
        uint i2 = min(eB.z & 0xffffu, (uint)(N_NODES - 1));
        uint i3 = min(eB.w & 0xffffu, (uint)(N_NODES - 1));
        vB0 = *((const uint4*)(H + ((size_t)i0 << 6) + (fg << 3)));
        vB1 = *((const uint4*)(H + ((size_t)i1 << 6) + (fg << 3)));
        vB2 = *((const uint4*)(H + ((size_t)i2 << 6) + (fg << 3)));
        vB3 = *((const uint4*)(H + ((size_t)i3 << 6) + (fg << 3)));
    }
    if (pA) {
        accum8(acc, vA0, wA0);
        accum8(acc, vA1, wA1);
        accum8(acc, vA2, wA2);
        accum8(acc, vA3, wA3);
    }
    if (pB) {
        accum8(acc, vB0, wB0);
        accum8(acc, vB1, wB1);
        accum8(acc, vB2, wB2);
        accum8(acc, vB3, wB3);
    }
    for (int base = 32; base < degv; base += 16) {   // rare (~3% of nodes)
        int s0 = base + j * 4;
        if (s0 < degv) {
            uint4 e = *((const uint4*)(bucket + s0));
            float w0 = hwf(e.x);
            float w1 = (s0 + 1 < degv) ? hwf(e.y) : 0.f;
            float w2 = (s0 + 2 < degv) ? hwf(e.z) : 0.f;
            float w3 = (s0 + 3 < degv) ? hwf(e.w) : 0.f;
            uint s0i = min(e.x & 0xffffu, (uint)(N_NODES - 1));
            uint s1i = min(e.y & 0xffffu, (uint)(N_NODES - 1));
            uint s2i = min(e.z & 0xffffu, (uint)(N_NODES - 1));
            uint s3i = min(e.w & 0xffffu, (uint)(N_NODES - 1));
            uint4 v0 = *((const uint4*)(H + ((size_t)s0i << 6) + (fg << 3)));
            uint4 v1 = *((const uint4*)(H + ((size_t)s1i << 6) + (fg << 3)));
            uint4 v2 = *((const uint4*)(H + ((size_t)s2i << 6) + (fg << 3)));
            uint4 v3 = *((const uint4*)(H + ((size_t)s3i << 6) + (fg << 3)));
            accum8(acc, v0, w0);
            accum8(acc, v1, w1);
            accum8(acc, v2, w2);
            accum8(acc, v3, w3);
        }
    }
    // reduce over the 4 quads of each 32-lane half (xor 8,16 stay in-half)
#pragma unroll
    for (int t = 0; t < 8; ++t) {
        acc[t] += __shfl_xor(acc[t], 8, 64);
        acc[t] += __shfl_xor(acc[t], 16, 64);
    }
}

// ---- fused: XCD-partitioned fill + H1 = X@W1 + weight-split prep (2 blocks) ----
__global__ __launch_bounds__(256) void fill_and_l1(const int* __restrict__ src,
                                                   const int* __restrict__ dst,
                                                   const float* __restrict__ w,
                                                   int* __restrict__ deg,
                                                   uint* __restrict__ csr,
                                                   const float* __restrict__ X,
                                                   const float* __restrict__ W,
                                                   const float* __restrict__ W2,
                                                   const float* __restrict__ Wd,
                                                   short* __restrict__ W2T2,
                                                   short* __restrict__ WdT2,
                                                   ushort* __restrict__ H) {
    __shared__ __align__(16) short sBT[2][D][72];    // 18.4 KB (aliased as rep later)
    int tid = threadIdx.x;

    if (blockIdx.x < FILL_BLOCKS) {
        // NGROUPS=4 (known-good FETCH profile; dst stays CACHED, re-scanned
        // 4x and L2/L3-absorbed). src/w are NT (read exactly once).
        // Scan unrolled and phase-batched.
        const int g = blockIdx.x & (NGROUPS - 1);
        const int s = blockIdx.x >> 2;               // slice 0..NSLICES-1
        const int lo = g * DST_PER_GROUP;
        const int e0 = s * 256 + tid;
        int d[KMAX];
        bool mk[KMAX];
#pragma unroll
        for (int k = 0; k < KMAX; ++k) {
            int e = e0 + k * FSTRIDE;
            int dv = (e < N_EDGES) ? dst[e] : -1;
            d[k] = dv;
            mk[k] = ((uint)(dv - lo) < (uint)DST_PER_GROUP);
        }
        float wv5[KMAX];
        int sv5[KMAX];
#pragma unroll
        for (int k = 0; k < KMAX; ++k)
            if (mk[k]) {
                int e = e0 + k * FSTRIDE;
                wv5[k] = __builtin_nontemporal_load(w + e);
                sv5[k] = __builtin_nontemporal_load(src + e);
            }
        int r5[KMAX];
#pragma unroll
        for (int k = 0; k < KMAX; ++k)
            if (mk[k]) r5[k] = atomicAdd(&deg[d[k]], 1);
#pragma unroll
        for (int k = 0; k < KMAX; ++k)
            if (mk[k]) {
                uint hw = (uint)__half_as_ushort(__float2half_rn(wv5[k]));
                uint payload = (uint)sv5[k] | (hw << 16);
                int r = min(r5[k], CAP - 1);         // safety clamp
                csr[(d[k] << 6) + r] = payload;
            }
        return;
    }

    if (blockIdx.x >= FILL_BLOCKS + MM_BLOCKS) {
        // ---------- weight-split prep ----------
        if (blockIdx.x == FILL_BLOCKS + MM_BLOCKS) {
            for (int idx = tid; idx < D * D; idx += 256) {
                int k = idx >> 6, c = idx & 63;
                float wv = W2[idx];
                ushort hi = f2bf(wv);
                W2T2[(size_t)c * D + k] = (short)hi;
                W2T2[(size_t)(D + c) * D + k] = (short)f2bf(wv - bf2f(hi));
            }
        } else {
            for (int idx = tid; idx < NCT * 16 * D; idx += 256) {
                int jj = idx >> 6, k = idx & 63;
                float wv = (jj < DHID) ? Wd[k * DHID + jj] : 0.f;
                ushort hi = f2bf(wv);
                WdT2[(size_t)jj * D + k] = (short)hi;
                WdT2[(size_t)(NCT * 16 + jj) * D + k] = (short)f2bf(wv - bf2f(hi));
            }
        }
        return;
    }

    // ---------- mfma_l1 path ----------
    for (int idx = tid; idx < D * D; idx += 256) {
        int k = idx >> 6, c = idx & 63;
        float wv = W[idx];
        ushort hi = f2bf(wv);
        sBT[0][c][k] = (short)hi;
        sBT[1][c][k] = (short)f2bf(wv - bf2f(hi));
    }
    __syncthreads();
    int wv_ = tid >> 6, lane = tid & 63, quad = lane >> 4, m = lane & 15;
    int tile = min((blockIdx.x - FILL_BLOCKS) * 4 + wv_, NTILES - 1);  // clamp (dup stores ok)
    int node0 = tile * 16;

    f32x4 acc[4] = {{0,0,0,0},{0,0,0,0},{0,0,0,0},{0,0,0,0}};
#pragma unroll
    for (int kt = 0; kt < 2; ++kt) {
        int k0 = kt * 32 + quad * 8;
        const float* xp = X + ((size_t)(node0 + m) << 6) + k0;
        f32x4 xa = __builtin_nontemporal_load((const f32x4*)xp);   // NT: X read-once
        f32x4 xb = __builtin_nontemporal_load((const f32x4*)(xp + 4));
        float xv[8] = {xa[0], xa[1], xa[2], xa[3], xb[0], xb[1], xb[2], xb[3]};
        s16x8 ahi, alo;
#pragma unroll
        for (int jj = 0; jj < 8; ++jj) {
            ushort hi = f2bf(xv[jj]);
            ahi[jj] = (short)hi;
            alo[jj] = (short)f2bf(xv[jj] - bf2f(hi));
        }
#pragma unroll
        for (int ct = 0; ct < 4; ++ct) {
            int n = ct * 16 + m;
            s16x8 bhi = *((const s16x8*)&sBT[0][n][k0]);
            s16x8 blo = *((const s16x8*)&sBT[1][n][k0]);
            acc[ct] = MFMA16(ahi, bhi, acc[ct]);
            acc[ct] = MFMA16(ahi, blo, acc[ct]);
            acc[ct] = MFMA16(alo, bhi, acc[ct]);
        }
    }
    __syncthreads();   // safe to alias rep over sBT
    short (*rep)[16][72] = (short(*)[16][72])&sBT[0][0][0];
#pragma unroll
    for (int ct = 0; ct < 4; ++ct)
#pragma unroll
        for (int r = 0; r < 4; ++r)
            rep[wv_][quad * 4 + r][ct * 16 + m] = (short)f2bf(acc[ct][r]);
#pragma unroll
    for (int half = 0; half < 2; ++half) {
        int r = (lane >> 3) + half * 8;
        int c0 = (lane & 7) * 8;
        s16x8 v = *((const s16x8*)&rep[wv_][r][c0]);
        *((s16x8*)(H + ((size_t)(node0 + r) << 6) + c0)) = v;
    }
}

// ---------------- gather + bias + swish -> bf16 activation (layer 1) ----------------
// Grid-stride, 2 nodes per wave, SOFTWARE-PIPELINED: each wave owns ~6
// node-pairs; the NEXT pair's bucket+deg loads are issued before the CURRENT
// pair's row-gather/FMA phase, hiding the bucket latency after iteration 0.
// (vmcnt is in-order: waiting on the current bucket does not drain the
// prefetch issued after it.)
__global__ __launch_bounds__(256) void gather_act(const ushort* __restrict__ H,
                                                  const int* __restrict__ deg,
                                                  const uint* __restrict__ csr,
                                                  const float* __restrict__ bias,
                                                  ushort* __restrict__ actOut) {
    int tid = threadIdx.x;
    int wave = tid >> 6, lane = tid & 63;
    int h = lane >> 5, j = (lane >> 3) & 3, fg = lane & 7;
    const int NPAIRS = N_NODES / 2;                  // 25000
    const int stride = GA_BLOCKS * 4;
    int pair = blockIdx.x * 4 + wave;
    if (pair >= NPAIRS) return;

    int node = pair * 2 + h;
    const uint* bucket = csr + ((size_t)node << 6);
    uint4 eA = *((const uint4*)(bucket + j * 4));
    uint4 eB = *((const uint4*)(bucket + 16 + j * 4));
    int degv = min(deg[node], CAP);

    for (;;) {
        int npair = pair + stride;
        bool more = (npair < NPAIRS);
        int nnode = more ? (npair * 2 + h) : node;   // clamp: safe dup prefetch
        const uint* nbucket = csr + ((size_t)nnode << 6);
        uint4 neA = *((const uint4*)(nbucket + j * 4));
        uint4 neB = *((const uint4*)(nbucket + 16 + j * 4));
        int ndeg = min(deg[nnode], CAP);

        float acc[8];
        gather_body(H, bucket, eA, eB, degv, j, fg, acc);
        if (j == 0) {
            float4 ba = ((const float4*)bias)[fg * 2];
            float4 bb = ((const float4*)bias)[fg * 2 + 1];
            float r0 = swishf(acc[0] + ba.x);
            float r1 = swishf(acc[1] + ba.y);
            float r2 = swishf(acc[2] + ba.z);
            float r3 = swishf(acc[3] + ba.w);
            float r4 = swishf(acc[4] + bb.x);
            float r5 = swishf(acc[5] + bb.y);
            float r6 = swishf(acc[6] + bb.z);
            float r7 = swishf(acc[7] + bb.w);
            uint4 u;
            u.x = (uint)f2bf(r0) | ((uint)f2bf(r1) << 16);
            u.y = (uint)f2bf(r2) | ((uint)f2bf(r3) << 16);
            u.z = (uint)f2bf(r4) | ((uint)f2bf(r5) << 16);
            u.w = (uint)f2bf(r6) | ((uint)f2bf(r7) << 16);
            *((uint4*)(actOut + ((size_t)node << 6) + (fg << 3))) = u;
        }

        if (!more) break;
        pair = npair; node = nnode; bucket = nbucket;
        eA = neA; eB = neB; degv = ndeg;
    }
}

// ---- fused: layer-2 gather + W2 matmul + bias + swish + MLP head, one 16-node tile/block ----
__global__ __launch_bounds__(256) void gather_tail(const ushort* __restrict__ act1,
                                                   const int* __restrict__ deg,
                                                   const uint* __restrict__ csr,
                                                   const short* __restrict__ W2T2,
                                                   const float* __restrict__ b2,
                                                   const short* __restrict__ WdT2,
                                                   const float* __restrict__ bd,
                                                   const float* __restrict__ Wo,
                                                   const float* __restrict__ bo,
                                                   float* __restrict__ out) {
    __shared__ __align__(16) float sAgg[16][72];    // 4.6 KB fp32 aggregates
    __shared__ __align__(16) short sAct2[16][72];   // 2.3 KB bf16 act2 tile
    __shared__ float sPart[4][16];                  // per-wave head partials
    int tid = threadIdx.x;
    int wv = tid >> 6, lane = tid & 63;
    int h = lane >> 5, j = (lane >> 3) & 3, fg = lane & 7;
    int quad = lane >> 4, m = lane & 15;
    int node0 = blockIdx.x * 16;

    // ---- phase 0: gather 4 nodes per wave, FUSED pair of passes ----
    // Both passes' bucket+deg loads issue up-front (independent), removing
    // one full bucket latency from the serial chain; node1's row loads
    // overlap node0's reduce/store epilogue.
    {
        int n0l = wv * 4 + h, n1l = wv * 4 + 2 + h;
        int n0 = node0 + n0l, n1 = node0 + n1l;
        const uint* b0 = csr + ((size_t)n0 << 6);
        const uint* b1 = csr + ((size_t)n1 << 6);
        uint4 eA0 = *((const uint4*)(b0 + j * 4));
        uint4 eB0 = *((const uint4*)(b0 + 16 + j * 4));
        uint4 eA1 = *((const uint4*)(b1 + j * 4));
        uint4 eB1 = *((const uint4*)(b1 + 16 + j * 4));
        int d0 = min(deg[n0], CAP);
        int d1 = min(deg[n1], CAP);

        float acc0[8];
        gather_body(act1, b0, eA0, eB0, d0, j, fg, acc0);
        if (j == 0) {
            float4 u0 = {acc0[0], acc0[1], acc0[2], acc0[3]};
            float4 u1 = {acc0[4], acc0[5], acc0[6], acc0[7]};
            *((float4*)&sAgg[n0l][fg * 8]) = u0;
            *((float4*)&sAgg[n0l][fg * 8 + 4]) = u1;
        }
        float acc1[8];
        gather_body(act1, b1, eA1, eB1, d1, j, fg, acc1);
        if (j == 0) {
            float4 u0 = {acc1[0], acc1[1], acc1[2], acc1[3]};
            float4 u1 = {acc1[4], acc1[5], acc1[6], acc1[7]};
            *((float4*)&sAgg[n1l][fg * 8]) = u0;
            *((float4*)&sAgg[n1l][fg * 8 + 4]) = u1;
        }
    }
    __syncthreads();

    // ---- phase A: act2 = swish(agg @ W2 + b2), wave wv -> col-tile wv ----
    {
        f32x4 acc = {0, 0, 0, 0};
        int n = wv * 16 + m;
#pragma unroll
        for (int kt = 0; kt < 2; ++kt) {
            int k0 = kt * 32 + quad * 8;
            float4 xa = *((const float4*)&sAgg[m][k0]);
            float4 xb = *((const float4*)&sAgg[m][k0 + 4]);
            float xv[8] = {xa.x, xa.y, xa.z, xa.w, xb.x, xb.y, xb.z, xb.w};
            s16x8 ahi, alo;
#pragma unroll
            for (int jj = 0; jj < 8; ++jj) {
                ushort hi = f2bf(xv[jj]);
                ahi[jj] = (short)hi;
                alo[jj] = (short)f2bf(xv[jj] - bf2f(hi));
            }
            s16x8 bhi = *((const s16x8*)(W2T2 + (size_t)n * D + k0));
            s16x8 blo = *((const s16x8*)(W2T2 + (size_t)(D + n) * D + k0));
            acc = MFMA16(ahi, bhi, acc);
            acc = MFMA16(ahi, blo, acc);
            acc = MFMA16(alo, bhi, acc);
        }
        float bv = b2[n];
#pragma unroll
        for (int r = 0; r < 4; ++r)
            sAct2[quad * 4 + r][n] = (short)f2bf(swishf(acc[r] + bv));
    }
    __syncthreads();

    // ---- phase B: head over col-tiles {wv, wv+4} ----
    float part[4] = {0, 0, 0, 0};
#pragma unroll
    for (int cc = 0; cc < 2; ++cc) {
        int ct = wv + cc * 4;
        if (ct < NCT) {
            f32x4 acc = {0, 0, 0, 0};
            int n = ct * 16 + m;
#pragma unroll
            for (int kt = 0; kt < 2; ++kt) {
                int k0 = kt * 32 + quad * 8;
                s16x8 a = *((const s16x8*)&sAct2[m][k0]);
                s16x8 bhi = *((const s16x8*)(WdT2 + (size_t)n * D + k0));
                s16x8 blo = *((const s16x8*)(WdT2 + (size_t)(NCT * 16 + n) * D + k0));
                acc = MFMA16(a, bhi, acc);
                acc = MFMA16(a, blo, acc);
            }
            float bdv = (n < DHID) ? bd[n] : 0.f;
            float wov = (n < DHID) ? Wo[n] : 0.f;
#pragma unroll
            for (int r = 0; r < 4; ++r)
                part[r] = fmaf(swishf(acc[r] + bdv), wov, part[r]);
        }
    }
#pragma unroll
    for (int r = 0; r < 4; ++r) {
        part[r] += __shfl_xor(part[r], 1, 64);
        part[r] += __shfl_xor(part[r], 2, 64);
        part[r] += __shfl_xor(part[r], 4, 64);
        part[r] += __shfl_xor(part[r], 8, 64);
    }
    if (m == 0) {
#pragma unroll
        for (int r = 0; r < 4; ++r)
            sPart[wv][quad * 4 + r] = part[r];
    }
    __syncthreads();
    if (tid < 16) {
        float z = sPart[0][tid] + sPart[1][tid] + sPart[2][tid] + sPart[3][tid] + bo[0];
        out[node0 + tid] = 1.f / (1.f + __expf(-z));
    }
}

extern "C" void kernel_launch(void* const* d_in, const int* in_sizes, int n_in,
                              void* d_out, int out_size, void* d_ws, size_t ws_size,
                              hipStream_t stream) {
    const float* x   = (const float*)d_in[0];
    const int* esrc  = (const int*)d_in[1];
    const int* edst  = (const int*)d_in[2];
    const float* ew  = (const float*)d_in[3];
    const float* W1  = (const float*)d_in[4];
    const float* b1  = (const float*)d_in[5];
    const float* W2  = (const float*)d_in[6];
    const float* b2  = (const float*)d_in[7];
    const float* Wd  = (const float*)d_in[8];
    const float* bd  = (const float*)d_in[9];
    const float* Wo  = (const float*)d_in[10];
    const float* bo  = (const float*)d_in[11];
    float* out = (float*)d_out;

    char* ws = (char*)d_ws;
    ushort* H1   = (ushort*)ws;  ws += (size_t)N_NODES * D * sizeof(ushort);   // 6.4 MB
    ushort* act1 = (ushort*)ws;  ws += (size_t)N_NODES * D * sizeof(ushort);   // 6.4 MB
    uint* csr    = (uint*)ws;    ws += (size_t)N_NODES * CAP * sizeof(uint);   // 12.8 MB (not zeroed)
    int* deg     = (int*)ws;     ws += (size_t)N_NODES * sizeof(int);          // 200 KB
    short* W2T2  = (short*)ws;   ws += (size_t)2 * D * D * sizeof(short);      // 16 KB
    short* WdT2  = (short*)ws;   ws += (size_t)2 * NCT * 16 * D * sizeof(short); // 28.7 KB

    // ---- only deg needs zeroing (200 KB) ----
    hipMemsetAsync(deg, 0, (size_t)N_NODES * sizeof(int), stream);

    // ---- fused: XCD-partitioned fill + layer-1 matmul + weight prep ----
    fill_and_l1<<<FILL_BLOCKS + MM_BLOCKS + 2, 256, 0, stream>>>(
        esrc, edst, ew, deg, csr, x, W1, W2, Wd, W2T2, WdT2, H1);

    // ---- layer 1 gather (+bias+swish), pipelined grid-stride ----
    gather_act<<<GA_BLOCKS, 256, 0, stream>>>(H1, deg, csr, b1, act1);

    // ---- fused: layer-2 gather + W2 matmul + swish + MLP head ----
    gather_tail<<<NTILES, 256, 0, stream>>>(act1, deg, csr, W2T2, b2, WdT2, bd, Wo, bo, out);
}

// Round 6
// 179.522 us; speedup vs baseline: 1.0382x; 1.0331x over previous
//
#include <hip/hip_runtime.h>
#include <hip/hip_fp16.h>

#define N_NODES 50000
#define N_EDGES 800000
#define D 64
#define DHID 100
#define NTILES (N_NODES / 16)                   // 3125
#define NCT 7                                   // head col-tiles (112 cols padded)
#define CAP 32                                  // slots per node = ONE 128B csr line
#define SPILL_MAX 8192                          // overflow edges (exp ~20)
#define NGROUPS 4                               // dst-range groups
#define NSLICES 780                             // fill blocks per group
#define FILL_BLOCKS (NGROUPS * NSLICES)         // 3120
#define MM_BLOCKS ((NTILES + 3) / 4)            // 782
#define DST_PER_GROUP (N_NODES / NGROUPS)       // 12500
#define FSTRIDE (NSLICES * 256)                 // 199680
#define KMAX 5                                  // scan iterations per thread (4 full + ragged)

typedef unsigned short ushort;
typedef unsigned int uint;
typedef __attribute__((ext_vector_type(8))) short s16x8;
typedef __attribute__((ext_vector_type(4))) float f32x4;

#define MFMA16(A, B, C) __builtin_amdgcn_mfma_f32_16x16x32_bf16((A), (B), (C), 0, 0, 0)

__device__ __forceinline__ float swishf(float x) { return x / (1.0f + __expf(-x)); }

__device__ __forceinline__ ushort f2bf(float f) {   // RTNE fp32 -> bf16
    uint u = __float_as_uint(f);
    uint r = (u + 0x7fffu + ((u >> 16) & 1u)) >> 16;
    return (ushort)r;
}
__device__ __forceinline__ float bf2f(ushort h) { return __uint_as_float((uint)h << 16); }
__device__ __forceinline__ float bf_lo(uint d) { return __uint_as_float(d << 16); }
__device__ __forceinline__ float bf_hi(uint d) { return __uint_as_float(d & 0xffff0000u); }

__device__ __forceinline__ float hwf(uint e) {
    return __half2float(__ushort_as_half((ushort)(e >> 16)));
}

__device__ __forceinline__ void accum8(float* acc, uint4 v, float w) {
    acc[0] = fmaf(w, bf_lo(v.x), acc[0]);
    acc[1] = fmaf(w, bf_hi(v.x), acc[1]);
    acc[2] = fmaf(w, bf_lo(v.y), acc[2]);
    acc[3] = fmaf(w, bf_hi(v.y), acc[3]);
    acc[4] = fmaf(w, bf_lo(v.z), acc[4]);
    acc[5] = fmaf(w, bf_hi(v.z), acc[5]);
    acc[6] = fmaf(w, bf_lo(v.w), acc[6]);
    acc[7] = fmaf(w, bf_hi(v.w), acc[7]);
}

// Gather body for one node (2 nodes per wave, half h owns one node).
// Bucket is ONE 128B line (CAP=32): grain A = slots j*4.., grain B = 16+j*4..
// eA/eB/degv are loaded by the caller so both grains + deg issue in one window.
// Slot >= CAP edges are handled by the spill pass (add_spills).
__device__ __forceinline__ void gather_body(const ushort* __restrict__ H,
                                            uint4 eA, uint4 eB, int degv,
                                            int j, int fg, float* acc) {
#pragma unroll
    for (int t = 0; t < 8; ++t) acc[t] = 0.f;
    const int sA = j * 4, sB = 16 + j * 4;
    bool pA = sA < degv, pB = sB < degv;
    uint4 vA0, vA1, vA2, vA3, vB0, vB1, vB2, vB3;
    float wA0 = 0, wA1 = 0, wA2 = 0, wA3 = 0;
    float wB0 = 0, wB1 = 0, wB2 = 0, wB3 = 0;
    if (pA) {                                        // issue A row loads
        wA0 = hwf(eA.x);
        wA1 = (sA + 1 < degv) ? hwf(eA.y) : 0.f;
        wA2 = (sA + 2 < degv) ? hwf(eA.z) : 0.f;
        wA3 = (sA + 3 < degv) ? hwf(eA.w) : 0.f;
        uint i0 = min(eA.x & 0xffffu, (uint)(N_NODES - 1));
        uint i1 = min(eA.y & 0xffffu, (uint)(N_NODES - 1));
        uint i2 = min(eA.z & 0xffffu, (uint)(N_NODES - 1));
        uint i3 = min(eA.w & 0xffffu, (uint)(N_NODES - 1));
        vA0 = *((const uint4*)(H + ((size_t)i0 << 6) + (fg << 3)));
        vA1 = *((const uint4*)(H + ((size_t)i1 << 6) + (fg << 3)));
        vA2 = *((const uint4*)(H + ((size_t)i2 << 6) + (fg << 3)));
        vA3 = *((const uint4*)(H + ((size_t)i3 << 6) + (fg << 3)));
    }
    if (pB) {                                        // issue B row loads before A's FMAs
        wB0 = hwf(eB.x);
        wB1 = (sB + 1 < degv) ? hwf(eB.y) : 0.f;
        wB2 = (sB + 2 < degv) ? hwf(eB.z) : 0.f;
        wB3 = (sB + 3 < degv) ? hwf(eB.w) : 0.f;
        uint i0 = min(eB.x & 0xffffu, (uint)(N_NODES - 1));
        uint i1 = min(eB.y & 0xffffu, (uint)(N_NODES - 1));
        uint i2 = min(eB.z & 0xffffu, (uint)(N_NODES - 1));
        uint i3 = min(eB.w & 0xffffu, (uint)(N_NODES - 1));
        vB0 = *((const uint4*)(H + ((size_t)i0 << 6) + (fg << 3)));
        vB1 = *((const uint4*)(H + ((size_t)i1 << 6) + (fg << 3)));
        vB2 = *((const uint4*)(H + ((size_t)i2 << 6) + (fg << 3)));
        vB3 = *((const uint4*)(H + ((size_t)i3 << 6) + (fg << 3)));
    }
    if (pA) {
        accum8(acc, vA0, wA0);
        accum8(acc, vA1, wA1);
        accum8(acc, vA2, wA2);
        accum8(acc, vA3, wA3);
    }
    if (pB) {
        accum8(acc, vB0, wB0);
        accum8(acc, vB1, wB1);
        accum8(acc, vB2, wB2);
        accum8(acc, vB3, wB3);
    }
    // reduce over the 4 quads of each 32-lane half (xor 8,16 stay in-half)
#pragma unroll
    for (int t = 0; t < 8; ++t) {
        acc[t] += __shfl_xor(acc[t], 8, 64);
        acc[t] += __shfl_xor(acc[t], 16, 64);
    }
}

// Overflow edges (slot >= CAP in fill). Runs on j==0 lanes AFTER the reduce:
// acc holds the node's full partial sum, add each matching spill edge.
// Expected nspill ~ 20 for the whole graph; list is L2-hot.
__device__ __forceinline__ void add_spills(const ushort* __restrict__ H,
                                           const int* __restrict__ spillCnt,
                                           const uint2* __restrict__ spill,
                                           int node, int fg, float* acc) {
    int n = min(*spillCnt, SPILL_MAX);
    for (int i = 0; i < n; ++i) {
        uint2 sp = spill[i];
        if ((int)sp.x == node) {
            float wv = hwf(sp.y);
            uint si = min(sp.y & 0xffffu, (uint)(N_NODES - 1));
            uint4 v = *((const uint4*)(H + ((size_t)si << 6) + (fg << 3)));
            accum8(acc, v, wv);
        }
    }
}

// ---- fused: XCD-partitioned fill + H1 = X@W1 + weight-split prep (2 blocks) ----
__global__ __launch_bounds__(256) void fill_and_l1(const int* __restrict__ src,
                                                   const int* __restrict__ dst,
                                                   const float* __restrict__ w,
                                                   int* __restrict__ deg,
                                                   uint* __restrict__ csr,
                                                   int* __restrict__ spillCnt,
                                                   uint2* __restrict__ spill,
                                                   const float* __restrict__ X,
                                                   const float* __restrict__ W,
                                                   const float* __restrict__ W2,
                                                   const float* __restrict__ Wd,
                                                   short* __restrict__ W2T2,
                                                   short* __restrict__ WdT2,
                                                   ushort* __restrict__ H) {
    __shared__ __align__(16) short sBT[2][D][72];    // 18.4 KB (aliased as rep later)
    int tid = threadIdx.x;

    if (blockIdx.x < FILL_BLOCKS) {
        // CAP=32: each node's bucket is ONE 128B line; a group's csr slab is
        // 1.6 MB -> stays L2-resident for the whole scan (no mid-kernel
        // partial-dirty eviction churn). dst CACHED (re-scanned 4x,
        // L2/L3-absorbed); src/w NT (read-once, keep them out of L2 so the
        // hot csr lines stay resident). Slot>=32 -> tiny global spill list.
        const int g = blockIdx.x & (NGROUPS - 1);
        const int s = blockIdx.x >> 2;               // slice 0..NSLICES-1
        const int lo = g * DST_PER_GROUP;
        const int e0 = s * 256 + tid;
        int d[KMAX];
        bool mk[KMAX];
#pragma unroll
        for (int k = 0; k < KMAX; ++k) {
            int e = e0 + k * FSTRIDE;
            int dv = (e < N_EDGES) ? dst[e] : -1;
            d[k] = dv;
            mk[k] = ((uint)(dv - lo) < (uint)DST_PER_GROUP);
        }
        float wv5[KMAX];
        int sv5[KMAX];
#pragma unroll
        for (int k = 0; k < KMAX; ++k)
            if (mk[k]) {
                int e = e0 + k * FSTRIDE;
                wv5[k] = __builtin_nontemporal_load(w + e);
                sv5[k] = __builtin_nontemporal_load(src + e);
            }
        int r5[KMAX];
#pragma unroll
        for (int k = 0; k < KMAX; ++k)
            if (mk[k]) r5[k] = atomicAdd(&deg[d[k]], 1);
#pragma unroll
        for (int k = 0; k < KMAX; ++k)
            if (mk[k]) {
                uint hw = (uint)__half_as_ushort(__float2half_rn(wv5[k]));
                uint payload = (uint)sv5[k] | (hw << 16);
                int r = r5[k];
                if (r < CAP) {
                    csr[(d[k] << 5) + r] = payload;
                } else {
                    int si = atomicAdd(spillCnt, 1);
                    if (si < SPILL_MAX) spill[si] = make_uint2((uint)d[k], payload);
                }
            }
        return;
    }

    if (blockIdx.x >= FILL_BLOCKS + MM_BLOCKS) {
        // ---------- weight-split prep ----------
        if (blockIdx.x == FILL_BLOCKS + MM_BLOCKS) {
            for (int idx = tid; idx < D * D; idx += 256) {
                int k = idx >> 6, c = idx & 63;
                float wv = W2[idx];
                ushort hi = f2bf(wv);
                W2T2[(size_t)c * D + k] = (short)hi;
                W2T2[(size_t)(D + c) * D + k] = (short)f2bf(wv - bf2f(hi));
            }
        } else {
            for (int idx = tid; idx < NCT * 16 * D; idx += 256) {
                int jj = idx >> 6, k = idx & 63;
                float wv = (jj < DHID) ? Wd[k * DHID + jj] : 0.f;
                ushort hi = f2bf(wv);
                WdT2[(size_t)jj * D + k] = (short)hi;
                WdT2[(size_t)(NCT * 16 + jj) * D + k] = (short)f2bf(wv - bf2f(hi));
            }
        }
        return;
    }

    // ---------- mfma_l1 path ----------
    for (int idx = tid; idx < D * D; idx += 256) {
        int k = idx >> 6, c = idx & 63;
        float wv = W[idx];
        ushort hi = f2bf(wv);
        sBT[0][c][k] = (short)hi;
        sBT[1][c][k] = (short)f2bf(wv - bf2f(hi));
    }
    __syncthreads();
    int wv_ = tid >> 6, lane = tid & 63, quad = lane >> 4, m = lane & 15;
    int tile = min((blockIdx.x - FILL_BLOCKS) * 4 + wv_, NTILES - 1);  // clamp (dup stores ok)
    int node0 = tile * 16;

    f32x4 acc[4] = {{0,0,0,0},{0,0,0,0},{0,0,0,0},{0,0,0,0}};
#pragma unroll
    for (int kt = 0; kt < 2; ++kt) {
        int k0 = kt * 32 + quad * 8;
        const float* xp = X + ((size_t)(node0 + m) << 6) + k0;
        f32x4 xa = __builtin_nontemporal_load((const f32x4*)xp);   // NT: X read-once
        f32x4 xb = __builtin_nontemporal_load((const f32x4*)(xp + 4));
        float xv[8] = {xa[0], xa[1], xa[2], xa[3], xb[0], xb[1], xb[2], xb[3]};
        s16x8 ahi, alo;
#pragma unroll
        for (int jj = 0; jj < 8; ++jj) {
            ushort hi = f2bf(xv[jj]);
            ahi[jj] = (short)hi;
            alo[jj] = (short)f2bf(xv[jj] - bf2f(hi));
        }
#pragma unroll
        for (int ct = 0; ct < 4; ++ct) {
            int n = ct * 16 + m;
            s16x8 bhi = *((const s16x8*)&sBT[0][n][k0]);
            s16x8 blo = *((const s16x8*)&sBT[1][n][k0]);
            acc[ct] = MFMA16(ahi, bhi, acc[ct]);
            acc[ct] = MFMA16(ahi, blo, acc[ct]);
            acc[ct] = MFMA16(alo, bhi, acc[ct]);
        }
    }
    __syncthreads();   // safe to alias rep over sBT
    short (*rep)[16][72] = (short(*)[16][72])&sBT[0][0][0];
#pragma unroll
    for (int ct = 0; ct < 4; ++ct)
#pragma unroll
        for (int r = 0; r < 4; ++r)
            rep[wv_][quad * 4 + r][ct * 16 + m] = (short)f2bf(acc[ct][r]);
#pragma unroll
    for (int half = 0; half < 2; ++half) {
        int r = (lane >> 3) + half * 8;
        int c0 = (lane & 7) * 8;
        s16x8 v = *((const s16x8*)&rep[wv_][r][c0]);
        *((s16x8*)(H + ((size_t)(node0 + r) << 6) + c0)) = v;
    }
}

// ---------------- gather + bias + swish -> bf16 activation (layer 1) ----------------
// 2 nodes per wave: 8 nodes per 256-thread block, full grid (R1-best config).
__global__ __launch_bounds__(256) void gather_act(const ushort* __restrict__ H,
                                                  const int* __restrict__ deg,
                                                  const uint* __restrict__ csr,
                                                  const int* __restrict__ spillCnt,
                                                  const uint2* __restrict__ spill,
                                                  const float* __restrict__ bias,
                                                  ushort* __restrict__ actOut) {
    int tid = threadIdx.x;
    int wave = tid >> 6, lane = tid & 63;
    int h = lane >> 5, j = (lane >> 3) & 3, fg = lane & 7;
    int node = blockIdx.x * 8 + wave * 2 + h;
    const uint* bucket = csr + ((size_t)node << 5);
    uint4 eA = *((const uint4*)(bucket + j * 4));        // same 128B line
    uint4 eB = *((const uint4*)(bucket + 16 + j * 4));
    int degv = min(deg[node], CAP);

    float acc[8];
    gather_body(H, eA, eB, degv, j, fg, acc);
    if (j == 0) {
        add_spills(H, spillCnt, spill, node, fg, acc);
        float4 ba = ((const float4*)bias)[fg * 2];
        float4 bb = ((const float4*)bias)[fg * 2 + 1];
        float r0 = swishf(acc[0] + ba.x);
        float r1 = swishf(acc[1] + ba.y);
        float r2 = swishf(acc[2] + ba.z);
        float r3 = swishf(acc[3] + ba.w);
        float r4 = swishf(acc[4] + bb.x);
        float r5 = swishf(acc[5] + bb.y);
        float r6 = swishf(acc[6] + bb.z);
        float r7 = swishf(acc[7] + bb.w);
        uint4 u;
        u.x = (uint)f2bf(r0) | ((uint)f2bf(r1) << 16);
        u.y = (uint)f2bf(r2) | ((uint)f2bf(r3) << 16);
        u.z = (uint)f2bf(r4) | ((uint)f2bf(r5) << 16);
        u.w = (uint)f2bf(r6) | ((uint)f2bf(r7) << 16);
        *((uint4*)(actOut + ((size_t)node << 6) + (fg << 3))) = u;
    }
}

// ---- fused: layer-2 gather + W2 matmul + bias + swish + MLP head, one 16-node tile/block ----
__global__ __launch_bounds__(256) void gather_tail(const ushort* __restrict__ act1,
                                                   const int* __restrict__ deg,
                                                   const uint* __restrict__ csr,
                                                   const int* __restrict__ spillCnt,
                                                   const uint2* __restrict__ spill,
                                                   const short* __restrict__ W2T2,
                                                   const float* __restrict__ b2,
                                                   const short* __restrict__ WdT2,
                                                   const float* __restrict__ bd,
                                                   const float* __restrict__ Wo,
                                                   const float* __restrict__ bo,
                                                   float* __restrict__ out) {
    __shared__ __align__(16) float sAgg[16][72];    // 4.6 KB fp32 aggregates
    __shared__ __align__(16) short sAct2[16][72];   // 2.3 KB bf16 act2 tile
    __shared__ float sPart[4][16];                  // per-wave head partials
    int tid = threadIdx.x;
    int wv = tid >> 6, lane = tid & 63;
    int h = lane >> 5, j = (lane >> 3) & 3, fg = lane & 7;
    int quad = lane >> 4, m = lane & 15;
    int node0 = blockIdx.x * 16;

    // ---- phase 0: gather 4 nodes per wave, both passes' bucket+deg up-front ----
    {
        int n0l = wv * 4 + h, n1l = wv * 4 + 2 + h;
        int n0 = node0 + n0l, n1 = node0 + n1l;
        const uint* b0 = csr + ((size_t)n0 << 5);
        const uint* b1 = csr + ((size_t)n1 << 5);
        uint4 eA0 = *((const uint4*)(b0 + j * 4));
        uint4 eB0 = *((const uint4*)(b0 + 16 + j * 4));
        uint4 eA1 = *((const uint4*)(b1 + j * 4));
        uint4 eB1 = *((const uint4*)(b1 + 16 + j * 4));
        int d0 = min(deg[n0], CAP);
        int d1 = min(deg[n1], CAP);

        float acc0[8];
        gather_body(act1, eA0, eB0, d0, j, fg, acc0);
        if (j == 0) {
            add_spills(act1, spillCnt, spill, n0, fg, acc0);
            float4 u0 = {acc0[0], acc0[1], acc0[2], acc0[3]};
            float4 u1 = {acc0[4], acc0[5], acc0[6], acc0[7]};
            *((float4*)&sAgg[n0l][fg * 8]) = u0;
            *((float4*)&sAgg[n0l][fg * 8 + 4]) = u1;
        }
        float acc1[8];
        gather_body(act1, eA1, eB1, d1, j, fg, acc1);
        if (j == 0) {
            add_spills(act1, spillCnt, spill, n1, fg, acc1);
            float4 u0 = {acc1[0], acc1[1], acc1[2], acc1[3]};
            float4 u1 = {acc1[4], acc1[5], acc1[6], acc1[7]};
            *((float4*)&sAgg[n1l][fg * 8]) = u0;
            *((float4*)&sAgg[n1l][fg * 8 + 4]) = u1;
        }
    }
    __syncthreads();

    // ---- phase A: act2 = swish(agg @ W2 + b2), wave wv -> col-tile wv ----
    {
        f32x4 acc = {0, 0, 0, 0};
        int n = wv * 16 + m;
#pragma unroll
        for (int kt = 0; kt < 2; ++kt) {
            int k0 = kt * 32 + quad * 8;
            float4 xa = *((const float4*)&sAgg[m][k0]);
            float4 xb = *((const float4*)&sAgg[m][k0 + 4]);
            float xv[8] = {xa.x, xa.y, xa.z, xa.w, xb.x, xb.y, xb.z, xb.w};
            s16x8 ahi, alo;
#pragma unroll
            for (int jj = 0; jj < 8; ++jj) {
                ushort hi = f2bf(xv[jj]);
                ahi[jj] = (short)hi;
                alo[jj] = (short)f2bf(xv[jj] - bf2f(hi));
            }
            s16x8 bhi = *((const s16x8*)(W2T2 + (size_t)n * D + k0));
            s16x8 blo = *((const s16x8*)(W2T2 + (size_t)(D + n) * D + k0));
            acc = MFMA16(ahi, bhi, acc);
            acc = MFMA16(ahi, blo, acc);
            acc = MFMA16(alo, bhi, acc);
        }
        float bv = b2[n];
#pragma unroll
        for (int r = 0; r < 4; ++r)
            sAct2[quad * 4 + r][n] = (short)f2bf(swishf(acc[r] + bv));
    }
    __syncthreads();

    // ---- phase B: head over col-tiles {wv, wv+4} ----
    float part[4] = {0, 0, 0, 0};
#pragma unroll
    for (int cc = 0; cc < 2; ++cc) {
        int ct = wv + cc * 4;
        if (ct < NCT) {
            f32x4 acc = {0, 0, 0, 0};
            int n = ct * 16 + m;
#pragma unroll
            for (int kt = 0; kt < 2; ++kt) {
                int k0 = kt * 32 + quad * 8;
                s16x8 a = *((const s16x8*)&sAct2[m][k0]);
                s16x8 bhi = *((const s16x8*)(WdT2 + (size_t)n * D + k0));
                s16x8 blo = *((const s16x8*)(WdT2 + (size_t)(NCT * 16 + n) * D + k0));
                acc = MFMA16(a, bhi, acc);
                acc = MFMA16(a, blo, acc);
            }
            float bdv = (n < DHID) ? bd[n] : 0.f;
            float wov = (n < DHID) ? Wo[n] : 0.f;
#pragma unroll
            for (int r = 0; r < 4; ++r)
                part[r] = fmaf(swishf(acc[r] + bdv), wov, part[r]);
        }
    }
#pragma unroll
    for (int r = 0; r < 4; ++r) {
        part[r] += __shfl_xor(part[r], 1, 64);
        part[r] += __shfl_xor(part[r], 2, 64);
        part[r] += __shfl_xor(part[r], 4, 64);
        part[r] += __shfl_xor(part[r], 8, 64);
    }
    if (m == 0) {
#pragma unroll
        for (int r = 0; r < 4; ++r)
            sPart[wv][quad * 4 + r] = part[r];
    }
    __syncthreads();
    if (tid < 16) {
        float z = sPart[0][tid] + sPart[1][tid] + sPart[2][tid] + sPart[3][tid] + bo[0];
        out[node0 + tid] = 1.f / (1.f + __expf(-z));
    }
}

extern "C" void kernel_launch(void* const* d_in, const int* in_sizes, int n_in,
                              void* d_out, int out_size, void* d_ws, size_t ws_size,
                              hipStream_t stream) {
    const float* x   = (const float*)d_in[0];
    const int* esrc  = (const int*)d_in[1];
    const int* edst  = (const int*)d_in[2];
    const float* ew  = (const float*)d_in[3];
    const float* W1  = (const float*)d_in[4];
    const float* b1  = (const float*)d_in[5];
    const float* W2  = (const float*)d_in[6];
    const float* b2  = (const float*)d_in[7];
    const float* Wd  = (const float*)d_in[8];
    const float* bd  = (const float*)d_in[9];
    const float* Wo  = (const float*)d_in[10];
    const float* bo  = (const float*)d_in[11];
    float* out = (float*)d_out;

    char* ws = (char*)d_ws;
    ushort* H1    = (ushort*)ws; ws += (size_t)N_NODES * D * sizeof(ushort);   // 6.4 MB
    ushort* act1  = (ushort*)ws; ws += (size_t)N_NODES * D * sizeof(ushort);   // 6.4 MB
    uint* csr     = (uint*)ws;   ws += (size_t)N_NODES * CAP * sizeof(uint);   // 6.4 MB (not zeroed)
    int* deg      = (int*)ws;    ws += (size_t)N_NODES * sizeof(int);          // 200 KB
    int* spillCnt = (int*)ws;    ws += 4 * sizeof(int);                        // adj. to deg
    uint2* spill  = (uint2*)ws;  ws += (size_t)SPILL_MAX * sizeof(uint2);      // 64 KB (not zeroed)
    short* W2T2   = (short*)ws;  ws += (size_t)2 * D * D * sizeof(short);      // 16 KB
    short* WdT2   = (short*)ws;  ws += (size_t)2 * NCT * 16 * D * sizeof(short); // 28.7 KB

    const int gBlocks = N_NODES / 8;   // 6250 (2 nodes per wave, full grid)

    // ---- zero deg + spillCnt in one memset (contiguous) ----
    hipMemsetAsync(deg, 0, (size_t)(N_NODES + 4) * sizeof(int), stream);

    // ---- fused: XCD-partitioned fill + layer-1 matmul + weight prep ----
    fill_and_l1<<<FILL_BLOCKS + MM_BLOCKS + 2, 256, 0, stream>>>(
        esrc, edst, ew, deg, csr, spillCnt, spill, x, W1, W2, Wd, W2T2, WdT2, H1);

    // ---- layer 1 gather (+bias+swish) ----
    gather_act<<<gBlocks, 256, 0, stream>>>(H1, deg, csr, spillCnt, spill, b1, act1);

    // ---- fused: layer-2 gather + W2 matmul + swish + MLP head ----
    gather_tail<<<NTILES, 256, 0, stream>>>(act1, deg, csr, spillCnt, spill,
                                            W2T2, b2, WdT2, bd, Wo, bo, out);
}